// Round 18
// baseline (24.901 us; speedup 1.0000x reference)
//
#include <hip/hip_runtime.h>

typedef short bf16x8 __attribute__((ext_vector_type(8)));
typedef float f32x4  __attribute__((ext_vector_type(4)));
typedef unsigned int u32;

#define HH 128
#define WW 128

__device__ __forceinline__ u32 cvt_pk_bf16(float lo, float hi) {
    u32 r;
    asm volatile("v_cvt_pk_bf16_f32 %0, %1, %2" : "=v"(r) : "v"(lo), "v"(hi));
    return r;   // low16 = bf16(lo), high16 = bf16(hi)
}

// LDS-only barrier (does not drain global loads/stores).
__device__ __forceinline__ void lds_barrier() {
    asm volatile("s_waitcnt lgkmcnt(0)" ::: "memory");
    __builtin_amdgcn_s_barrier();
    __builtin_amdgcn_sched_barrier(0);
}

// Implicit-GEMM conv via 9 shifted 32x32 channel GEMMs on mfma_f32_16x16x32_bf16.
// = R15 (best, 21.26us) + ONE change: rows 6..9's cvt+LDS-write deferred to
// overlap chunk0's compute (their global loads still issue at cycle 0).
// Block: 1024 thr (16 waves) owns 8 contiguous output rows of one batch.
// Pipeline: [20 loads issue] [coop ctx+weight synth] [cvt rows 0..5] barrier
//   [chunk0 compute (slots 0..5) || cvt rows 6..9 -> slots 6..9] barrier
//   [chunk0 bounce epilogue (slots 0..3)] [chunk1 compute (slots 4..9),
//   overlapping chunk0's nontemporal store drain] [chunk1 epilogue].
// Wave = (row4 0..3, nq 0..3): 1 row, 2 col-tiles, all 32 out-ch.
// Grid: 256 blocks (16 b x 16 groups), XCD-bijective swizzle, 1 block/CU.
__global__ __launch_bounds__(1024, 1) void geps_mfma_kernel(
    const float* __restrict__ x, const float* __restrict__ codes,
    const float* __restrict__ weight, const float* __restrict__ A,
    const float* __restrict__ Bm, const float* __restrict__ bias,
    const float* __restrict__ bctx, float* __restrict__ out)
{
    __shared__ bf16x8 lds_x[5120];    // [10 slots][512 entries] = 80 KB (+ bounce)
    __shared__ bf16x8 lds_w[1152];    // [9 kl][2 oh][4 kb][16 o] x 8i bf16
    __shared__ float  lds_ctx[576];
    __shared__ float  lds_b[32];

    const int tid  = threadIdx.x;
    const int l    = tid & 63;
    const int wvid = tid >> 6;         // 0..15
    const int row4 = wvid >> 2;        // 0..3 (row within 4-row chunk)
    const int nq   = wvid & 3;         // 0..3 (col-tiles nq*2, nq*2+1)

    // XCD-aware bijective swizzle: 256 blocks = 8 XCDs x 32 contiguous.
    const int orig = blockIdx.x;
    const int vb   = (orig & 7) * 32 + (orig >> 3);
    const int b    = vb >> 4;          // batch 0..15
    const int grp  = vb & 15;          // 8-row group 0..15
    const int h0   = grp * 8;

    // ---- Issue ALL x loads now (rows h0-1..h0+8); 5 items x 4 float2 ----
    float2 f[3][4];    // rows 0..5 (cvt early)
    float2 fd[2][4];   // rows 6..9 (cvt deferred under chunk0 compute)
    #pragma unroll
    for (int it = 0; it < 3; ++it) {
        int idx = it * 1024 + tid;     // < 3072
        int cp = idx & 63, jh = (idx >> 6) & 1, ig = (idx >> 7) & 3, rr = idx >> 9;
        int grow = (h0 - 1 + rr) & 127;
        const float* src =
            x + ((size_t)(b * 32 + ig * 8 + jh * 4) * HH + grow) * WW + cp * 2;
        #pragma unroll
        for (int jj = 0; jj < 4; ++jj)
            f[it][jj] = *(const float2*)(src + (size_t)jj * HH * WW);
    }
    #pragma unroll
    for (int it = 0; it < 2; ++it) {
        int idx = it * 1024 + tid;     // < 2048
        int cp = idx & 63, jh = (idx >> 6) & 1, ig = (idx >> 7) & 3;
        int rr = 6 + (idx >> 9);       // 6..9
        int grow = (h0 - 1 + rr) & 127;
        const float* src =
            x + ((size_t)(b * 32 + ig * 8 + jh * 4) * HH + grow) * WW + cp * 2;
        #pragma unroll
        for (int jj = 0; jj < 4; ++jj)
            fd[it][jj] = *(const float2*)(src + (size_t)jj * HH * WW);
    }

    // ---- ctx + bias (cooperative, overlaps load latency) ----
    const float c00 = codes[b * 4 + 0];
    const float c01 = codes[b * 4 + 1];
    const float c10 = codes[b * 4 + 2];
    const float c11 = codes[b * 4 + 3];
    if (tid < 576) {
        int j = tid;
        int i = j / 18, rem = j % 18, r = rem / 9, kl = rem % 9;
        float a0 = A[(i * 2 + 0) * 9 + kl];
        float a1 = A[(i * 2 + 1) * 9 + kl];
        lds_ctx[j] = (r == 0) ? (a0 * c00 + a1 * c10) : (a0 * c01 + a1 * c11);
    }
    if (tid < 32) lds_b[tid] = bias[tid] + c00 * bctx[tid] + c11 * bctx[32 + tid];
    lds_barrier();   // ctx visible

    // ---- Weight synthesis -> bf16 LDS (cooperative, coalesced) ----
    for (int j = tid; j < 1152; j += 1024) {
        int kl = j >> 7, rem = j & 127, o = rem >> 2, kb = rem & 3;
        float m0 = Bm[(o * 2 + 0) * 9 + kl];
        float m1 = Bm[(o * 2 + 1) * 9 + kl];
        float wf[8];
        #pragma unroll
        for (int jj = 0; jj < 8; ++jj) {
            int i = kb * 8 + jj;
            wf[jj] = weight[(o * 32 + i) * 9 + kl]
                   + lds_ctx[i * 18 + kl] * m0
                   + lds_ctx[i * 18 + 9 + kl] * m1;
        }
        u32 pk[4];
        #pragma unroll
        for (int q = 0; q < 4; ++q) pk[q] = cvt_pk_bf16(wf[2 * q], wf[2 * q + 1]);
        *(uint4*)&lds_w[kl * 128 + (o >> 4) * 64 + kb * 16 + (o & 15)] =
            make_uint4(pk[0], pk[1], pk[2], pk[3]);
    }

    // ---- Convert + write rows 0..5 only (waits loads per-item) ----
    #pragma unroll
    for (int it = 0; it < 3; ++it) {
        int idx = it * 1024 + tid;
        int cp = idx & 63, jh = (idx >> 6) & 1, ig = (idx >> 7) & 3, rr = idx >> 9;
        int c0 = cp * 2;
        u32 a0 = cvt_pk_bf16(f[it][0].x, f[it][1].x);
        u32 a1 = cvt_pk_bf16(f[it][2].x, f[it][3].x);
        u32 b0 = cvt_pk_bf16(f[it][0].y, f[it][1].y);
        u32 b1 = cvt_pk_bf16(f[it][2].y, f[it][3].y);
        int didx = (c0 >> 4) * 64 + ig * 16 + (c0 & 15);
        *(uint2*)((char*)lds_x + rr * 8192 + didx * 16 + jh * 8) =
            make_uint2(a0, a1);
        *(uint2*)((char*)lds_x + rr * 8192 + (didx + 1) * 16 + jh * 8) =
            make_uint2(b0, b1);
    }
    lds_barrier();   // slots 0..5 + weights complete

    // ---- A fragments: all 9 taps x both oh halves (72 VGPRs) ----
    const int awb = (l >> 4) * 16 + (l & 15);
    bf16x8 af[9][2];
    #pragma unroll
    for (int kl = 0; kl < 9; ++kl)
        #pragma unroll
        for (int oh = 0; oh < 2; ++oh)
            af[kl][oh] = lds_w[kl * 128 + oh * 64 + awb];

    // ---- B-address bases per tap-column shift dl in {-1,0,1} ----
    const int p = l & 15, igf = l >> 4;
    int bb[3];
    #pragma unroll
    for (int dl = -1; dl <= 1; ++dl) {
        int pq = p + dl;                       // -1..16
        bb[dl + 1] = (pq & 15) + ((pq >> 4) << 6) + igf * 16;  // 16B-elem units
    }

    float blr[2][4];
    #pragma unroll
    for (int oh = 0; oh < 2; ++oh)
        #pragma unroll
        for (int r = 0; r < 4; ++r)
            blr[oh][r] = lds_b[oh * 16 + (l >> 4) * 4 + r];

    // ================== Chunk 0: rows h0+row4, slots row4..row4+2 ==========
    f32x4 acc[2][2];
    #pragma unroll
    for (int oh = 0; oh < 2; ++oh)
        #pragma unroll
        for (int q = 0; q < 2; ++q) acc[oh][q] = (f32x4){0.f, 0.f, 0.f, 0.f};

    #pragma unroll
    for (int lc = 0; lc < 3; ++lc) {
        #pragma unroll
        for (int k = 0; k < 3; ++k) {
            const bf16x8 a0 = af[k * 3 + lc][0];
            const bf16x8 a1 = af[k * 3 + lc][1];
            const int s = row4 + k;
            #pragma unroll
            for (int q = 0; q < 2; ++q) {
                int t = (bb[lc] + (nq * 2 + q) * 64) & 511;  // col wrap
                bf16x8 bfv = lds_x[s * 512 + t];
                acc[0][q] = __builtin_amdgcn_mfma_f32_16x16x32_bf16(
                    a0, bfv, acc[0][q], 0, 0, 0);
                acc[1][q] = __builtin_amdgcn_mfma_f32_16x16x32_bf16(
                    a1, bfv, acc[1][q], 0, 0, 0);
            }
        }
    }

    // ---- Deferred cvt rows 6..9 -> slots 6..9 (overlaps chunk0 compute;
    //      disjoint from chunk0 reads 0..5 and bounce 0..3) ----
    #pragma unroll
    for (int it = 0; it < 2; ++it) {
        int idx = it * 1024 + tid;
        int cp = idx & 63, jh = (idx >> 6) & 1, ig = (idx >> 7) & 3;
        int rr = 6 + (idx >> 9);
        int c0 = cp * 2;
        u32 a0 = cvt_pk_bf16(fd[it][0].x, fd[it][1].x);
        u32 a1 = cvt_pk_bf16(fd[it][2].x, fd[it][3].x);
        u32 b0 = cvt_pk_bf16(fd[it][0].y, fd[it][1].y);
        u32 b1 = cvt_pk_bf16(fd[it][2].y, fd[it][3].y);
        int didx = (c0 >> 4) * 64 + ig * 16 + (c0 & 15);
        *(uint2*)((char*)lds_x + rr * 8192 + didx * 16 + jh * 8) =
            make_uint2(a0, a1);
        *(uint2*)((char*)lds_x + rr * 8192 + (didx + 1) * 16 + jh * 8) =
            make_uint2(b0, b1);
    }

    // ---- Chunk0 coalesced epilogue: bounce slots 0..3 ----
    {
        float* bounce = (float*)lds_x;
        #pragma unroll
        for (int oh = 0; oh < 2; ++oh) {
            lds_barrier();   // chunk0 reads + slot 6..9 writes ordered
            #pragma unroll
            for (int q = 0; q < 2; ++q)
                #pragma unroll
                for (int r = 0; r < 4; ++r) {
                    int o16  = (l >> 4) * 4 + r;
                    int col  = (nq * 2 + q) * 16 + (l & 15);
                    int col2 = (col + o16 * 4) & 127;
                    bounce[(o16 * 4 + row4) * 128 + col2] =
                        acc[oh][q][r] + blr[oh][r];
                }
            lds_barrier();
            const int ch = oh * 16 + wvid;
            #pragma unroll
            for (int k2 = 0; k2 < 2; ++k2) {
                int hrow = 2 * k2 + (l >> 5);
                int lcol = (l & 31) * 4;
                int pcol = (lcol + wvid * 4) & 127;
                f32x4 v = *(const f32x4*)&bounce[(wvid * 4 + hrow) * 128 + pcol];
                __builtin_nontemporal_store(
                    v, (f32x4*)&out[((size_t)(b * 32 + ch) * HH + (h0 + hrow)) *
                                    WW + lcol]);
            }
        }
    }

    // ================== Chunk 1: rows h0+4+row4, slots 4..9 ================
    // No extra barrier; chunk1 compute overlaps chunk0's store drain.
    #pragma unroll
    for (int oh = 0; oh < 2; ++oh)
        #pragma unroll
        for (int q = 0; q < 2; ++q) acc[oh][q] = (f32x4){0.f, 0.f, 0.f, 0.f};

    #pragma unroll
    for (int lc = 0; lc < 3; ++lc) {
        #pragma unroll
        for (int k = 0; k < 3; ++k) {
            const bf16x8 a0 = af[k * 3 + lc][0];
            const bf16x8 a1 = af[k * 3 + lc][1];
            const int s = 4 + row4 + k;
            #pragma unroll
            for (int q = 0; q < 2; ++q) {
                int t = (bb[lc] + (nq * 2 + q) * 64) & 511;
                bf16x8 bfv = lds_x[s * 512 + t];
                acc[0][q] = __builtin_amdgcn_mfma_f32_16x16x32_bf16(
                    a0, bfv, acc[0][q], 0, 0, 0);
                acc[1][q] = __builtin_amdgcn_mfma_f32_16x16x32_bf16(
                    a1, bfv, acc[1][q], 0, 0, 0);
            }
        }
    }

    // ---- Chunk1 coalesced epilogue: bounce slots 4..7 ----
    {
        float* bounce = (float*)((char*)lds_x + 4 * 8192);
        #pragma unroll
        for (int oh = 0; oh < 2; ++oh) {
            lds_barrier();   // all chunk1 LDS reads done
            #pragma unroll
            for (int q = 0; q < 2; ++q)
                #pragma unroll
                for (int r = 0; r < 4; ++r) {
                    int o16  = (l >> 4) * 4 + r;
                    int col  = (nq * 2 + q) * 16 + (l & 15);
                    int col2 = (col + o16 * 4) & 127;
                    bounce[(o16 * 4 + row4) * 128 + col2] =
                        acc[oh][q][r] + blr[oh][r];
                }
            lds_barrier();
            const int ch = oh * 16 + wvid;
            #pragma unroll
            for (int k2 = 0; k2 < 2; ++k2) {
                int hrow = 2 * k2 + (l >> 5);
                int lcol = (l & 31) * 4;
                int pcol = (lcol + wvid * 4) & 127;
                f32x4 v = *(const f32x4*)&bounce[(wvid * 4 + hrow) * 128 + pcol];
                __builtin_nontemporal_store(
                    v, (f32x4*)&out[((size_t)(b * 32 + ch) * HH +
                                     (h0 + 4 + hrow)) * WW + lcol]);
            }
        }
    }
}

extern "C" void kernel_launch(void* const* d_in, const int* in_sizes, int n_in,
                              void* d_out, int out_size, void* d_ws, size_t ws_size,
                              hipStream_t stream) {
    const float* x      = (const float*)d_in[0];
    const float* codes  = (const float*)d_in[1];
    const float* weight = (const float*)d_in[2];
    const float* A      = (const float*)d_in[3];
    const float* Bm     = (const float*)d_in[4];
    const float* bias   = (const float*)d_in[5];
    const float* bctx   = (const float*)d_in[6];
    float* out = (float*)d_out;

    hipLaunchKernelGGL(geps_mfma_kernel, dim3(256), dim3(1024), 0, stream,
                       x, codes, weight, A, Bm, bias, bctx, out);
}

// Round 19
// 21.293 us; speedup vs baseline: 1.1694x; 1.1694x over previous
//
#include <hip/hip_runtime.h>

typedef short bf16x8 __attribute__((ext_vector_type(8)));
typedef float f32x4  __attribute__((ext_vector_type(4)));
typedef unsigned int u32;

#define HH 128
#define WW 128

__device__ __forceinline__ u32 cvt_pk_bf16(float lo, float hi) {
    u32 r;
    asm volatile("v_cvt_pk_bf16_f32 %0, %1, %2" : "=v"(r) : "v"(lo), "v"(hi));
    return r;   // low16 = bf16(lo), high16 = bf16(hi)
}

// LDS-only barrier (does not drain global loads/stores).
__device__ __forceinline__ void lds_barrier() {
    asm volatile("s_waitcnt lgkmcnt(0)" ::: "memory");
    __builtin_amdgcn_s_barrier();
    __builtin_amdgcn_sched_barrier(0);
}

// Implicit-GEMM conv via 9 shifted 32x32 channel GEMMs on mfma_f32_16x16x32_bf16.
// == R15, the measured optimum (21.26 us) ==
// Block: 1024 thr (16 waves) owns 8 contiguous output rows of one batch.
// Prologue: all 20 x-loads issued at cycle 0 (512B-contiguous per instr),
// cooperative ctx+weight synthesis overlaps load latency, one staging pass
// into a flat 10-slot LDS buffer.
// Rows processed as TWO 4-row chunks.  Chunk0: compute -> coalesced bounce
// epilogue (bounce reuses slots 0..3, freed by chunk0's compute).  Chunk1
// compute starts with NO barrier (slots 4..9 disjoint from bounce), so
// chunk0's nontemporal store burst drains underneath it.
// Wave = (row4 0..3, nq 0..3): 1 row, 2 col-tiles, all 32 out-ch.
// Grid: 256 blocks (16 b x 16 groups), XCD-bijective swizzle, 1 block/CU.
__global__ __launch_bounds__(1024, 1) void geps_mfma_kernel(
    const float* __restrict__ x, const float* __restrict__ codes,
    const float* __restrict__ weight, const float* __restrict__ A,
    const float* __restrict__ Bm, const float* __restrict__ bias,
    const float* __restrict__ bctx, float* __restrict__ out)
{
    __shared__ bf16x8 lds_x[5120];    // [10 slots][512 entries] = 80 KB (+ bounce)
    __shared__ bf16x8 lds_w[1152];    // [9 kl][2 oh][4 kb][16 o] x 8i bf16
    __shared__ float  lds_ctx[576];
    __shared__ float  lds_b[32];

    const int tid  = threadIdx.x;
    const int l    = tid & 63;
    const int wvid = tid >> 6;         // 0..15
    const int row4 = wvid >> 2;        // 0..3 (row within 4-row chunk)
    const int nq   = wvid & 3;         // 0..3 (col-tiles nq*2, nq*2+1)

    // XCD-aware bijective swizzle: 256 blocks = 8 XCDs x 32 contiguous.
    const int orig = blockIdx.x;
    const int vb   = (orig & 7) * 32 + (orig >> 3);
    const int b    = vb >> 4;          // batch 0..15
    const int grp  = vb & 15;          // 8-row group 0..15
    const int h0   = grp * 8;

    // ---- Issue ALL x loads now (rows h0-1..h0+8); 5 items x 4 float2 ----
    float2 f[5][4];
    #pragma unroll
    for (int it = 0; it < 5; ++it) {
        int idx = it * 1024 + tid;     // < 5120
        int cp = idx & 63, jh = (idx >> 6) & 1, ig = (idx >> 7) & 3, rr = idx >> 9;
        int grow = (h0 - 1 + rr) & 127;
        const float* src =
            x + ((size_t)(b * 32 + ig * 8 + jh * 4) * HH + grow) * WW + cp * 2;
        #pragma unroll
        for (int jj = 0; jj < 4; ++jj)
            f[it][jj] = *(const float2*)(src + (size_t)jj * HH * WW);
    }

    // ---- ctx + bias (overlaps load latency) ----
    const float c00 = codes[b * 4 + 0];
    const float c01 = codes[b * 4 + 1];
    const float c10 = codes[b * 4 + 2];
    const float c11 = codes[b * 4 + 3];
    if (tid < 576) {
        int j = tid;
        int i = j / 18, rem = j % 18, r = rem / 9, kl = rem % 9;
        float a0 = A[(i * 2 + 0) * 9 + kl];
        float a1 = A[(i * 2 + 1) * 9 + kl];
        lds_ctx[j] = (r == 0) ? (a0 * c00 + a1 * c10) : (a0 * c01 + a1 * c11);
    }
    if (tid < 32) lds_b[tid] = bias[tid] + c00 * bctx[tid] + c11 * bctx[32 + tid];
    lds_barrier();   // ctx visible

    // ---- Weight synthesis -> bf16 LDS (still overlapping load latency) ----
    for (int j = tid; j < 1152; j += 1024) {
        int kl = j >> 7, rem = j & 127, o = rem >> 2, kb = rem & 3;
        float m0 = Bm[(o * 2 + 0) * 9 + kl];
        float m1 = Bm[(o * 2 + 1) * 9 + kl];
        float wf[8];
        #pragma unroll
        for (int jj = 0; jj < 8; ++jj) {
            int i = kb * 8 + jj;
            wf[jj] = weight[(o * 32 + i) * 9 + kl]
                   + lds_ctx[i * 18 + kl] * m0
                   + lds_ctx[i * 18 + 9 + kl] * m1;
        }
        u32 pk[4];
        #pragma unroll
        for (int q = 0; q < 4; ++q) pk[q] = cvt_pk_bf16(wf[2 * q], wf[2 * q + 1]);
        *(uint4*)&lds_w[kl * 128 + (o >> 4) * 64 + kb * 16 + (o & 15)] =
            make_uint4(pk[0], pk[1], pk[2], pk[3]);
    }

    // ---- Convert + write staged x to LDS ----
    #pragma unroll
    for (int it = 0; it < 5; ++it) {
        int idx = it * 1024 + tid;
        int cp = idx & 63, jh = (idx >> 6) & 1, ig = (idx >> 7) & 3, rr = idx >> 9;
        int c0 = cp * 2;
        u32 a0 = cvt_pk_bf16(f[it][0].x, f[it][1].x);
        u32 a1 = cvt_pk_bf16(f[it][2].x, f[it][3].x);
        u32 b0 = cvt_pk_bf16(f[it][0].y, f[it][1].y);
        u32 b1 = cvt_pk_bf16(f[it][2].y, f[it][3].y);
        int didx = (c0 >> 4) * 64 + ig * 16 + (c0 & 15);
        *(uint2*)((char*)lds_x + rr * 8192 + didx * 16 + jh * 8) =
            make_uint2(a0, a1);
        *(uint2*)((char*)lds_x + rr * 8192 + (didx + 1) * 16 + jh * 8) =
            make_uint2(b0, b1);
    }
    lds_barrier();   // staging + weights complete

    // ---- A fragments: all 9 taps x both oh halves (72 VGPRs) ----
    const int awb = (l >> 4) * 16 + (l & 15);
    bf16x8 af[9][2];
    #pragma unroll
    for (int kl = 0; kl < 9; ++kl)
        #pragma unroll
        for (int oh = 0; oh < 2; ++oh)
            af[kl][oh] = lds_w[kl * 128 + oh * 64 + awb];

    // ---- B-address bases per tap-column shift dl in {-1,0,1} ----
    const int p = l & 15, igf = l >> 4;
    int bb[3];
    #pragma unroll
    for (int dl = -1; dl <= 1; ++dl) {
        int pq = p + dl;                       // -1..16
        bb[dl + 1] = (pq & 15) + ((pq >> 4) << 6) + igf * 16;  // 16B-elem units
    }

    float blr[2][4];
    #pragma unroll
    for (int oh = 0; oh < 2; ++oh)
        #pragma unroll
        for (int r = 0; r < 4; ++r)
            blr[oh][r] = lds_b[oh * 16 + (l >> 4) * 4 + r];

    // ---- Two 4-row chunks: compute -> bounce epilogue; chunk1 compute
    //      overlaps chunk0's store drain (no barrier between). ----
    #pragma unroll
    for (int c = 0; c < 2; ++c) {
        // Compute chunk c: output rows h0+4c+row4, slots 4c+row4+k.
        f32x4 acc[2][2];
        #pragma unroll
        for (int oh = 0; oh < 2; ++oh)
            #pragma unroll
            for (int q = 0; q < 2; ++q) acc[oh][q] = (f32x4){0.f, 0.f, 0.f, 0.f};

        #pragma unroll
        for (int lc = 0; lc < 3; ++lc) {
            #pragma unroll
            for (int k = 0; k < 3; ++k) {
                const bf16x8 a0 = af[k * 3 + lc][0];
                const bf16x8 a1 = af[k * 3 + lc][1];
                const int s = 4 * c + row4 + k;
                #pragma unroll
                for (int q = 0; q < 2; ++q) {
                    int t = (bb[lc] + (nq * 2 + q) * 64) & 511;  // col wrap
                    bf16x8 bfv = lds_x[s * 512 + t];
                    acc[0][q] = __builtin_amdgcn_mfma_f32_16x16x32_bf16(
                        a0, bfv, acc[0][q], 0, 0, 0);
                    acc[1][q] = __builtin_amdgcn_mfma_f32_16x16x32_bf16(
                        a1, bfv, acc[1][q], 0, 0, 0);
                }
            }
        }

        // Coalesced epilogue: bounce region = slots 4c..4c+3 (32 KB), freed
        // by chunk c's own compute (chunk1 reads slots 4..9 only).
        float* bounce = (float*)((char*)lds_x + 4 * c * 8192);
        #pragma unroll
        for (int oh = 0; oh < 2; ++oh) {
            lds_barrier();   // compute reads (c) / previous round reads done
            #pragma unroll
            for (int q = 0; q < 2; ++q)
                #pragma unroll
                for (int r = 0; r < 4; ++r) {
                    int o16  = (l >> 4) * 4 + r;
                    int col  = (nq * 2 + q) * 16 + (l & 15);
                    int col2 = (col + o16 * 4) & 127;
                    bounce[(o16 * 4 + row4) * 128 + col2] =
                        acc[oh][q][r] + blr[oh][r];
                }
            lds_barrier();
            const int ch = oh * 16 + wvid;   // wave w streams channel oh*16+w
            #pragma unroll
            for (int k2 = 0; k2 < 2; ++k2) {
                int hrow = 2 * k2 + (l >> 5);
                int lcol = (l & 31) * 4;
                int pcol = (lcol + wvid * 4) & 127;
                f32x4 v = *(const f32x4*)&bounce[(wvid * 4 + hrow) * 128 + pcol];
                __builtin_nontemporal_store(
                    v, (f32x4*)&out[((size_t)(b * 32 + ch) * HH +
                                     (h0 + 4 * c + hrow)) * WW + lcol]);
            }
        }
        if (c == 0) lds_barrier();   // order bounce reads before chunk1's
        // LDS activity (cheap; chunk1 compute still overlaps store drain).
    }
}

extern "C" void kernel_launch(void* const* d_in, const int* in_sizes, int n_in,
                              void* d_out, int out_size, void* d_ws, size_t ws_size,
                              hipStream_t stream) {
    const float* x      = (const float*)d_in[0];
    const float* codes  = (const float*)d_in[1];
    const float* weight = (const float*)d_in[2];
    const float* A      = (const float*)d_in[3];
    const float* Bm     = (const float*)d_in[4];
    const float* bias   = (const float*)d_in[5];
    const float* bctx   = (const float*)d_in[6];
    float* out = (float*)d_out;

    hipLaunchKernelGGL(geps_mfma_kernel, dim3(256), dim3(1024), 0, stream,
                       x, codes, weight, A, Bm, bias, bctx, out);
}